// Round 18
// baseline (21437.556 us; speedup 1.0000x reference)
//
#include <hip/hip_runtime.h>
#include <stdint.h>

#define T_STEPS 256
#define BATCH   8192

// Reference semantics (proven, round-16 P0 + round-17 pass):
//   cur  = sum_k fmaf(w[k], s_k, acc) ascending, single acc; + bias at end
//   mem' = fmaf(0.95, mem, cur) - reset    (reset from OLD mem)
//   spike = mem' > 1.0
__device__ __forceinline__ float lif_update(float mem, float cur) {
#pragma clang fp contract(off)
    float reset = (mem > 1.0f) ? 1.0f : 0.0f;
    return fmaf(0.95f, mem, cur) - reset;
}

// uniform lane-broadcast of a float (compiles to v_readlane -> SGPR)
__device__ __forceinline__ float rl(float v, int k) {
    return __int_as_float(__builtin_amdgcn_readlane(__float_as_int(v), k));
}

__global__ __launch_bounds__(256, 2)
void snn_kernel(const float* __restrict__ left, const float* __restrict__ right,
                const float* __restrict__ ctx,
                const float* __restrict__ Wl1, const float* __restrict__ bl1,
                const float* __restrict__ Wl2, const float* __restrict__ bl2,
                const float* __restrict__ Wr1, const float* __restrict__ br1,
                const float* __restrict__ Wr2, const float* __restrict__ br2,
                const float* __restrict__ Wc,  const float* __restrict__ bc,
                const float* __restrict__ Wf,  const float* __restrict__ bf,
                const float* __restrict__ Wf2, const float* __restrict__ bf2,
                const float* __restrict__ Wo,  const float* __restrict__ bo,
                float* __restrict__ out)
{
    const int lane  = threadIdx.x & 63;
    const int gwave = blockIdx.x * 4 + (threadIdx.x >> 6);   // 0..4095
    const int b0 = gwave;                   // element 0
    const int b1 = gwave + BATCH / 2;       // element 1

    const int j32 = lane & 31;
    const int jc  = lane & 15;
    const int jf2 = (lane < 48) ? lane : 47;
    const int n_o = lane >> 4;

    // ---- Wo staged in LDS (read as float4, 4 broadcast addresses) ----
    __shared__ float wo_s[4 * 48];
    for (int i = threadIdx.x; i < 4 * 48; i += 256) wo_s[i] = Wo[i];
    __syncthreads();
    const float4* wo4 = reinterpret_cast<const float4*>(&wo_s[n_o * 48]);

    // ---- per-lane weights (shared by both batch elements) ----
    float w1[6], w2[32], wcr[3], wf[80], wf2r[64];
    const float* W1row = (lane < 32) ? (Wl1 + lane * 6)  : (Wr1 + j32 * 6);
    const float* W2row = (lane < 32) ? (Wl2 + lane * 32) : (Wr2 + j32 * 32);
    const float  bb1   = (lane < 32) ? bl1[lane] : br1[j32];
    const float  bb2   = (lane < 32) ? bl2[lane] : br2[j32];
#pragma unroll
    for (int k = 0; k < 6;  ++k) w1[k]  = W1row[k];
#pragma unroll
    for (int k = 0; k < 32; ++k) w2[k]  = W2row[k];
#pragma unroll
    for (int k = 0; k < 3;  ++k) wcr[k] = Wc[jc * 3 + k];
    const float bcr = bc[jc];
#pragma unroll
    for (int k = 0; k < 80; ++k) wf[k]  = Wf[lane * 80 + k];
    const float bfr = bf[lane];
#pragma unroll
    for (int k = 0; k < 64; ++k) wf2r[k] = Wf2[jf2 * 64 + k];
    const float bf2r = bf2[jf2];
    const float bor = bo[n_o];

    // ---- membrane state, 2 elements ----
    float ml1_0 = 0.f, ml2_0 = 0.f, mc_0 = 0.f, mf_0 = 0.f, mf2_0 = 0.f, mo_0 = 0.f;
    float ml1_1 = 0.f, ml2_1 = 0.f, mc_1 = 0.f, mf_1 = 0.f, mf2_1 = 0.f, mo_1 = 0.f;

    for (int t = 0; t < T_STEPS; ++t) {
        const size_t base0 = (size_t)t * BATCH + b0;
        const size_t base1 = (size_t)t * BATCH + b1;

        // ---- one ballot carries both elements' inputs (disjoint lanes) ----
        // e0: left lanes 0-5, ctx 8-10, right 32-37
        // e1: left lanes 16-21, ctx 24-26, right 48-53
        float vin = 0.f;
        if (lane < 6)                     vin = left [base0 * 6 + lane];
        else if (lane >= 16 && lane < 22) vin = left [base1 * 6 + (lane - 16)];
        else if (lane >= 8  && lane < 11) vin = ctx  [base0 * 3 + (lane - 8)];
        else if (lane >= 24 && lane < 27) vin = ctx  [base1 * 3 + (lane - 24)];
        else if (lane >= 32 && lane < 38) vin = right[base0 * 6 + (lane - 32)];
        else if (lane >= 48 && lane < 54) vin = right[base1 * 6 + (lane - 48)];
        const uint64_t in_mask = __ballot(vin > 0.5f);
        const uint32_t side = (lane < 32) ? (uint32_t)in_mask
                                          : (uint32_t)(in_mask >> 32);

        // ---- l1/r1: mask path (P0 arithmetic: bfe+cvt+fmac) ----
        {
            const uint32_t m0 = side & 0x3Fu;
            const uint32_t m1 = (side >> 16) & 0x3Fu;
            float a0 = 0.f, a1 = 0.f;
#pragma unroll
            for (int k = 0; k < 6; ++k) {
                a0 = fmaf(w1[k], (float)((m0 >> k) & 1u), a0);
                a1 = fmaf(w1[k], (float)((m1 >> k) & 1u), a1);
            }
            ml1_0 = lif_update(ml1_0, a0 + bb1);
            ml1_1 = lif_update(ml1_1, a1 + bb1);
        }
        const uint64_t s1_0 = __ballot(ml1_0 > 1.0f);
        const uint64_t s1_1 = __ballot(ml1_1 > 1.0f);

        // ---- l2/r2: mask path ----
        {
            const uint32_t m0 = (lane < 32) ? (uint32_t)s1_0 : (uint32_t)(s1_0 >> 32);
            const uint32_t m1 = (lane < 32) ? (uint32_t)s1_1 : (uint32_t)(s1_1 >> 32);
            float a0 = 0.f, a1 = 0.f;
#pragma unroll
            for (int k = 0; k < 32; ++k) {
                a0 = fmaf(w2[k], (float)((m0 >> k) & 1u), a0);
                a1 = fmaf(w2[k], (float)((m1 >> k) & 1u), a1);
            }
            ml2_0 = lif_update(ml2_0, a0 + bb2);
            ml2_1 = lif_update(ml2_1, a1 + bb2);
        }
        // spike floats: lane j holds fused bit j (l2 on 0-31, r2 on 32-63)
        const float s2f_0 = (ml2_0 > 1.0f) ? 1.0f : 0.0f;
        const float s2f_1 = (ml2_1 > 1.0f) ? 1.0f : 0.0f;

        // ---- c: mask path (real on lanes 0-15) ----
        {
            const uint32_t m0 = ((uint32_t)in_mask >> 8)  & 0x7u;
            const uint32_t m1 = ((uint32_t)in_mask >> 24) & 0x7u;
            float a0 = 0.f, a1 = 0.f;
#pragma unroll
            for (int k = 0; k < 3; ++k) {
                a0 = fmaf(wcr[k], (float)((m0 >> k) & 1u), a0);
                a1 = fmaf(wcr[k], (float)((m1 >> k) & 1u), a1);
            }
            mc_0 = lif_update(mc_0, a0 + bcr);
            mc_1 = lif_update(mc_1, a1 + bcr);
        }
        const float scf_0 = (mc_0 > 1.0f) ? 1.0f : 0.0f;   // lanes 0-15 real
        const float scf_1 = (mc_1 > 1.0f) ? 1.0f : 0.0f;

        // ---- f: 80 MACs via readlane broadcast (uniform SGPR operand) ----
        {
            float a0 = 0.f, a1 = 0.f;
#pragma unroll
            for (int k = 0; k < 64; ++k) {
                a0 = fmaf(wf[k], rl(s2f_0, k), a0);
                a1 = fmaf(wf[k], rl(s2f_1, k), a1);
            }
#pragma unroll
            for (int k = 0; k < 16; ++k) {
                a0 = fmaf(wf[64 + k], rl(scf_0, k), a0);
                a1 = fmaf(wf[64 + k], rl(scf_1, k), a1);
            }
            mf_0 = lif_update(mf_0, a0 + bfr);
            mf_1 = lif_update(mf_1, a1 + bfr);
        }
        const float sff_0 = (mf_0 > 1.0f) ? 1.0f : 0.0f;
        const float sff_1 = (mf_1 > 1.0f) ? 1.0f : 0.0f;

        // ---- f2: 64 MACs via readlane ----
        {
            float a0 = 0.f, a1 = 0.f;
#pragma unroll
            for (int k = 0; k < 64; ++k) {
                a0 = fmaf(wf2r[k], rl(sff_0, k), a0);
                a1 = fmaf(wf2r[k], rl(sff_1, k), a1);
            }
            mf2_0 = lif_update(mf2_0, a0 + bf2r);
            mf2_1 = lif_update(mf2_1, a1 + bf2r);
        }
        const float sf2f_0 = (mf2_0 > 1.0f) ? 1.0f : 0.0f;  // lanes 0-47 real
        const float sf2f_1 = (mf2_1 > 1.0f) ? 1.0f : 0.0f;

        // ---- o: 48 MACs, weights from LDS float4, spikes via readlane ----
        {
            float a0 = 0.f, a1 = 0.f;
#pragma unroll
            for (int q = 0; q < 12; ++q) {
                const float4 w4 = wo4[q];
                const float* wq = reinterpret_cast<const float*>(&w4);
#pragma unroll
                for (int j = 0; j < 4; ++j) {
                    const int k = q * 4 + j;
                    a0 = fmaf(wq[j], rl(sf2f_0, k), a0);
                    a1 = fmaf(wq[j], rl(sf2f_1, k), a1);
                }
            }
            mo_0 = lif_update(mo_0, a0 + bor);
            mo_1 = lif_update(mo_1, a1 + bor);
            if ((lane & 15) == 0) {
                out[base0 * 4 + n_o] = (mo_0 > 1.0f) ? 1.0f : 0.0f;
                out[base1 * 4 + n_o] = (mo_1 > 1.0f) ? 1.0f : 0.0f;
            }
        }
    }
}

extern "C" void kernel_launch(void* const* d_in, const int* in_sizes, int n_in,
                              void* d_out, int out_size, void* d_ws, size_t ws_size,
                              hipStream_t stream) {
    const float* left  = (const float*)d_in[0];
    const float* right = (const float*)d_in[1];
    const float* ctx   = (const float*)d_in[2];
    const float* Wl1   = (const float*)d_in[3];
    const float* bl1   = (const float*)d_in[4];
    const float* Wl2   = (const float*)d_in[5];
    const float* bl2   = (const float*)d_in[6];
    const float* Wr1   = (const float*)d_in[7];
    const float* br1   = (const float*)d_in[8];
    const float* Wr2   = (const float*)d_in[9];
    const float* br2   = (const float*)d_in[10];
    const float* Wc    = (const float*)d_in[11];
    const float* bc    = (const float*)d_in[12];
    const float* Wf    = (const float*)d_in[13];
    const float* bf    = (const float*)d_in[14];
    const float* Wf2   = (const float*)d_in[15];
    const float* bf2   = (const float*)d_in[16];
    const float* Wo    = (const float*)d_in[17];
    const float* bo    = (const float*)d_in[18];
    float* out = (float*)d_out;

    // 4096 waves x 2 elements each
    hipLaunchKernelGGL(snn_kernel, dim3(1024), dim3(256), 0, stream,
                       left, right, ctx, Wl1, bl1, Wl2, bl2, Wr1, br1, Wr2, br2,
                       Wc, bc, Wf, bf, Wf2, bf2, Wo, bo, out);
}

// Round 19
// 2597.028 us; speedup vs baseline: 8.2546x; 8.2546x over previous
//
#include <hip/hip_runtime.h>
#include <stdint.h>

#define T_STEPS 256
#define BATCH   8192

// Reference semantics (proven, round-16 P0 + round-17 pass, absmax=0):
//   cur  = sum_k fmaf(w[k], s_k, acc) ascending, single acc; + bias at end
//   mem' = fmaf(0.95, mem, cur) - reset    (reset from OLD mem, {0,1})
//   spike = mem' > 1.0
__device__ __forceinline__ float lif_update(float mem, float cur) {
#pragma clang fp contract(off)
    float reset = (mem > 1.0f) ? 1.0f : 0.0f;
    return fmaf(0.95f, mem, cur) - reset;
}

// wave-uniform mask bit -> float {0.0,1.0}; mask is an SGPR (ballot result),
// so this lowers to SALU s_lshr/s_and + s_cselect_b32 (no VALU ops).
__device__ __forceinline__ float ubit(uint32_t mask, int k) {
    return ((mask >> k) & 1u) ? 1.0f : 0.0f;
}

__global__ __launch_bounds__(256, 2)
void snn_kernel(const float* __restrict__ left, const float* __restrict__ right,
                const float* __restrict__ ctx,
                const float* __restrict__ Wl1, const float* __restrict__ bl1,
                const float* __restrict__ Wl2, const float* __restrict__ bl2,
                const float* __restrict__ Wr1, const float* __restrict__ br1,
                const float* __restrict__ Wr2, const float* __restrict__ br2,
                const float* __restrict__ Wc,  const float* __restrict__ bc,
                const float* __restrict__ Wf,  const float* __restrict__ bf,
                const float* __restrict__ Wf2, const float* __restrict__ bf2,
                const float* __restrict__ Wo,  const float* __restrict__ bo,
                float* __restrict__ out)
{
    const int lane = threadIdx.x & 63;
    const int b    = blockIdx.x * 4 + (threadIdx.x >> 6);

    const int j32 = lane & 31;
    const int jc  = lane & 15;
    const int jf2 = (lane < 48) ? lane : 47;  // lanes 48-63 shadow, excluded from ballot
    const int n_o = lane >> 4;

    // ---- Wo staged in LDS once (4x48 floats; float4 reads in hot loop) ----
    __shared__ float wo_s[4 * 48];
    for (int i = threadIdx.x; i < 4 * 48; i += 256) wo_s[i] = Wo[i];
    __syncthreads();
    const float4* wo4 = reinterpret_cast<const float4*>(&wo_s[n_o * 48]);

    // ---- per-lane weights in registers (identical to round-17 layout) ----
    float w1[6], w2[32], wcr[3], wf[80], wf2r[64];
    const float* W1row = (lane < 32) ? (Wl1 + lane * 6)  : (Wr1 + j32 * 6);
    const float* W2row = (lane < 32) ? (Wl2 + lane * 32) : (Wr2 + j32 * 32);
    const float  b1    = (lane < 32) ? bl1[lane] : br1[j32];
    const float  b2    = (lane < 32) ? bl2[lane] : br2[j32];
#pragma unroll
    for (int k = 0; k < 6;  ++k) w1[k]  = W1row[k];
#pragma unroll
    for (int k = 0; k < 32; ++k) w2[k]  = W2row[k];
#pragma unroll
    for (int k = 0; k < 3;  ++k) wcr[k] = Wc[jc * 3 + k];
    const float bcr = bc[jc];
#pragma unroll
    for (int k = 0; k < 80; ++k) wf[k]  = Wf[lane * 80 + k];
    const float bfr = bf[lane];
#pragma unroll
    for (int k = 0; k < 64; ++k) wf2r[k] = Wf2[jf2 * 64 + k];
    const float bf2r = bf2[jf2];
    const float bor = bo[n_o];

    // ---- membrane state (registers, persists across T) ----
    float ml1 = 0.f, ml2 = 0.f, mc = 0.f, mf = 0.f, mf2 = 0.f, mo = 0.f;

    for (int t = 0; t < T_STEPS; ++t) {
        const size_t base = (size_t)t * BATCH + b;

        // ---- inputs: lanes 0-5 left, 32-37 right, 8-10 ctx -> one ballot ----
        float vin = 0.f;
        if (lane < 6)                     vin = left [base * 6 + lane];
        else if (lane >= 32 && lane < 38) vin = right[base * 6 + (lane - 32)];
        else if (lane >= 8 && lane < 11)  vin = ctx  [base * 3 + (lane - 8)];
        const uint64_t in_mask = __ballot(vin > 0.5f);
        const uint32_t inLo = (uint32_t)in_mask;
        const uint32_t inHi = (uint32_t)(in_mask >> 32);

        // ---- l1/r1: dual uniform accumulation (SALU bit decode), per-lane select ----
        {
            float aLo = 0.f, aHi = 0.f;
#pragma unroll
            for (int k = 0; k < 6; ++k) {
                aLo = fmaf(w1[k], ubit(inLo, k), aLo);
                aHi = fmaf(w1[k], ubit(inHi, k), aHi);
            }
            const float acc = (lane < 32) ? aLo : aHi;
            ml1 = lif_update(ml1, acc + b1);
        }
        const uint64_t s1 = __ballot(ml1 > 1.0f);   // lo32 = s_l1, hi32 = s_r1
        const uint32_t s1Lo = (uint32_t)s1, s1Hi = (uint32_t)(s1 >> 32);

        // ---- l2/r2: dual uniform accumulation ----
        {
            float aLo = 0.f, aHi = 0.f;
#pragma unroll
            for (int k = 0; k < 32; ++k) {
                aLo = fmaf(w2[k], ubit(s1Lo, k), aLo);
                aHi = fmaf(w2[k], ubit(s1Hi, k), aHi);
            }
            const float acc = (lane < 32) ? aLo : aHi;
            ml2 = lif_update(ml2, acc + b2);
        }
        const uint64_t s2 = __ballot(ml2 > 1.0f);   // lo32 = s_l2, hi32 = s_r2
        const uint32_t s2Lo = (uint32_t)s2, s2Hi = (uint32_t)(s2 >> 32);

        // ---- c: mask uniform for all lanes (bits 8-10 of inLo) ----
        {
            float acc = 0.f;
#pragma unroll
            for (int k = 0; k < 3; ++k)
                acc = fmaf(wcr[k], ubit(inLo, 8 + k), acc);
            mc = lif_update(mc, acc + bcr);
        }
        const uint32_t sc = (uint32_t)__ballot((lane < 16) && (mc > 1.0f));

        // ---- f: 80 MACs, all masks wave-uniform -> 1 VALU fmac per MAC ----
        {
            float acc = 0.f;
#pragma unroll
            for (int k = 0; k < 32; ++k)
                acc = fmaf(wf[k],      ubit(s2Lo, k), acc);
#pragma unroll
            for (int k = 0; k < 32; ++k)
                acc = fmaf(wf[32 + k], ubit(s2Hi, k), acc);
#pragma unroll
            for (int k = 0; k < 16; ++k)
                acc = fmaf(wf[64 + k], ubit(sc, k), acc);
            mf = lif_update(mf, acc + bfr);
        }
        const uint64_t sf = __ballot(mf > 1.0f);
        const uint32_t sfLo = (uint32_t)sf, sfHi = (uint32_t)(sf >> 32);

        // ---- f2: 64 MACs, uniform masks ----
        {
            float acc = 0.f;
#pragma unroll
            for (int k = 0; k < 32; ++k)
                acc = fmaf(wf2r[k],      ubit(sfLo, k), acc);
#pragma unroll
            for (int k = 0; k < 32; ++k)
                acc = fmaf(wf2r[32 + k], ubit(sfHi, k), acc);
            mf2 = lif_update(mf2, acc + bf2r);
        }
        const uint64_t sf2 = __ballot((lane < 48) && (mf2 > 1.0f));
        const uint32_t f2Lo = (uint32_t)sf2, f2Hi = (uint32_t)(sf2 >> 32);

        // ---- o: 48 MACs, LDS float4 weights + uniform masks ----
        {
            float acc = 0.f;
#pragma unroll
            for (int q = 0; q < 12; ++q) {
                const float4 w4 = wo4[q];
#pragma unroll
                for (int j = 0; j < 4; ++j) {
                    const int k = q * 4 + j;
                    const float su = (k < 32) ? ubit(f2Lo, k) : ubit(f2Hi, k - 32);
                    acc = fmaf(reinterpret_cast<const float*>(&w4)[j], su, acc);
                }
            }
            mo = lif_update(mo, acc + bor);
            if ((lane & 15) == 0)
                out[base * 4 + n_o] = (mo > 1.0f) ? 1.0f : 0.0f;
        }
    }
}

extern "C" void kernel_launch(void* const* d_in, const int* in_sizes, int n_in,
                              void* d_out, int out_size, void* d_ws, size_t ws_size,
                              hipStream_t stream) {
    const float* left  = (const float*)d_in[0];
    const float* right = (const float*)d_in[1];
    const float* ctx   = (const float*)d_in[2];
    const float* Wl1   = (const float*)d_in[3];
    const float* bl1   = (const float*)d_in[4];
    const float* Wl2   = (const float*)d_in[5];
    const float* bl2   = (const float*)d_in[6];
    const float* Wr1   = (const float*)d_in[7];
    const float* br1   = (const float*)d_in[8];
    const float* Wr2   = (const float*)d_in[9];
    const float* br2   = (const float*)d_in[10];
    const float* Wc    = (const float*)d_in[11];
    const float* bc    = (const float*)d_in[12];
    const float* Wf    = (const float*)d_in[13];
    const float* bf    = (const float*)d_in[14];
    const float* Wf2   = (const float*)d_in[15];
    const float* bf2   = (const float*)d_in[16];
    const float* Wo    = (const float*)d_in[17];
    const float* bo    = (const float*)d_in[18];
    float* out = (float*)d_out;

    hipLaunchKernelGGL(snn_kernel, dim3(BATCH / 4), dim3(256), 0, stream,
                       left, right, ctx, Wl1, bl1, Wl2, bl2, Wr1, br1, Wr2, br2,
                       Wc, bc, Wf, bf, Wf2, bf2, Wo, bo, out);
}